// Round 4
// baseline (438.541 us; speedup 1.0000x reference)
//
#include <hip/hip_runtime.h>
#include <cstdint>
#include <cstddef>

// GAT layer, N=8192, Fin=128, Fout=64.
// h = elu( softmax_j(mask(leaky_relu(Wh1_i + Wh2_j))) @ Wh )
// R8 = R7 with ONE change: adj loads are plain (cached) instead of
// __builtin_nontemporal_load. NT was the constant across all ~3.3 TB/s
// attempts (R4/R5/R7); the 6.3 TB/s copy ceiling was measured with plain
// loads. Testing whether the nt cache policy halves streaming BW.
// phaseB structure: coalesced adj loads (4 rows x 256B fully-used lines
// per instr) -> wave-private LDS double-buffer with XOR bank swizzle ->
// ds_read_b128 fragments. LDS decouples fragment waits (lgkmcnt) from the HBM
// prefetch queue (vmcnt); depth-2 prefetch (8KB/wave) never drained because
// all L2-hot loads issue BEFORE the adj prefetch each tile (in-order vmcnt).

#define NN   8192
#define FIN  128
#define FOUT 64
#define SJ   8                 // j-split per row-tile: 512*SJ = 4096 wave-tasks
#define JCHUNK (NN / SJ)       // 1024 columns per wave -> 16 tiles of 64 cols

typedef __attribute__((ext_vector_type(8))) short   short8;   // 8 bf16 (4 VGPRs)
typedef __attribute__((ext_vector_type(4))) float   f32x4;

#define LOG2E 1.44269504088896340736f
#define NTL(p) (*(const f32x4*)(p))   // R8: plain cached load (was nontemporal)

// ---------------------------------------------------------------- Phase A ---
// One wave per 4 rows: Wh[row][f] (f = lane), store bf16 transposed
// Whbt[f][row], wave-reduce Wh1 = Wh.a1, Wh2 = Wh.a2 (pre-scaled by log2e so
// phaseB uses exp2 directly; leaky_relu commutes with positive scaling).
__global__ __launch_bounds__(256) void gat_phaseA(
    const float* __restrict__ x, const float* __restrict__ W,
    const float* __restrict__ a, unsigned short* __restrict__ Whbt,
    float* __restrict__ Wh1, float* __restrict__ Wh2)
{
  const int wid  = threadIdx.x >> 6;
  const int lane = threadIdx.x & 63;
  const int row0 = (blockIdx.x * 4 + wid) * 4;
  const float a1 = a[lane];
  const float a2 = a[FOUT + lane];
  float acc[4] = {0.f, 0.f, 0.f, 0.f};
#pragma unroll 4
  for (int k = 0; k < FIN; k += 4) {
    float4 wv0 = make_float4(W[(k+0)*FOUT + lane], W[(k+1)*FOUT + lane],
                             W[(k+2)*FOUT + lane], W[(k+3)*FOUT + lane]);
#pragma unroll
    for (int r = 0; r < 4; ++r) {
      float4 xv = *(const float4*)(x + (row0 + r) * FIN + k);
      acc[r] = fmaf(xv.x, wv0.x, acc[r]);
      acc[r] = fmaf(xv.y, wv0.y, acc[r]);
      acc[r] = fmaf(xv.z, wv0.z, acc[r]);
      acc[r] = fmaf(xv.w, wv0.w, acc[r]);
    }
  }
#pragma unroll
  for (int r = 0; r < 4; ++r) {
    // bf16 round-to-nearest-even
    unsigned int u = __float_as_uint(acc[r]);
    unsigned int rb = (u + 0x7FFFu + ((u >> 16) & 1u)) >> 16;
    Whbt[lane * NN + row0 + r] = (unsigned short)rb;
    float s1 = acc[r] * a1, s2 = acc[r] * a2;
#pragma unroll
    for (int off = 32; off; off >>= 1) {
      s1 += __shfl_xor(s1, off);
      s2 += __shfl_xor(s2, off);
    }
    if (lane == 0) { Wh1[row0 + r] = s1 * LOG2E; Wh2[row0 + r] = s2 * LOG2E; }
  }
}

// ---------------------------------------------------------------- Phase B ---
// Wave task = (rowTile of 16 rows) x (j-chunk of 1024). Tile = 16 rows x 64
// cols of adj (4 KB), double-buffered in wave-private LDS. Per tile section:
//   ds_write staged bank -> [b-frag/Wh2 loads] -> sb(0) -> [adj prefetch t+2,
//   coalesced] -> sb(0) -> 2 MFMA-blocks from swizzled ds_read_b128.
// Swizzle: LDS[m*256 + (x ^ ((m&7)<<4))] = adj[m][x/4] (x = byte in 256B row).
#define AF_MFMA(AD0, AD1, W20, W21, B0, B1, B2, B3)                      \
  {                                                                      \
    short8 af;                                                           \
    _Pragma("unroll")                                                    \
    for (int e = 0; e < 4; ++e) {                                        \
      float t0 = wh1 + (W20)[e];                                         \
      t0 = fmaxf(t0, 0.2f * t0);          /* leaky_relu, scale-inv */    \
      float p0 = exp2f(t0) * (AD0)[e];    /* mask: adj is 0.0/1.0 */     \
      unsigned int pu0 = __float_as_uint(p0) & 0xFFFF0000u;              \
      rsum += __uint_as_float(pu0);       /* denom matches bf16 num */   \
      af[e] = (short)(pu0 >> 16);                                        \
      float t1 = wh1 + (W21)[e];                                         \
      t1 = fmaxf(t1, 0.2f * t1);                                         \
      float p1 = exp2f(t1) * (AD1)[e];                                   \
      unsigned int pu1 = __float_as_uint(p1) & 0xFFFF0000u;              \
      rsum += __uint_as_float(pu1);                                      \
      af[4 + e] = (short)(pu1 >> 16);                                    \
    }                                                                    \
    c0 = __builtin_amdgcn_mfma_f32_16x16x32_bf16(af, B0, c0, 0, 0, 0);   \
    c1 = __builtin_amdgcn_mfma_f32_16x16x32_bf16(af, B1, c1, 0, 0, 0);   \
    c2 = __builtin_amdgcn_mfma_f32_16x16x32_bf16(af, B2, c2, 0, 0, 0);   \
    c3 = __builtin_amdgcn_mfma_f32_16x16x32_bf16(af, B3, c3, 0, 0, 0);   \
  }

#define BLOCKC(BUF, BOFF, W20, W21, B0, B1, B2, B3)                      \
  {                                                                      \
    f32x4 ad0 = *(const f32x4*)((BUF) + rA + (BOFF));                    \
    f32x4 ad1 = *(const f32x4*)((BUF) + rB + (BOFF));                    \
    AF_MFMA(ad0, ad1, W20, W21, B0, B1, B2, B3)                          \
  }

// One tile section: ST* = staged bank regs, BUF = lds buffer, JB = col base,
// SOFF = src byte offset for the prefetch (tile idx +2), PF = do prefetch.
#define TILE_SECTION(ST0, ST1, ST2, ST3, BUF, JB, SOFF, PF)              \
  {                                                                      \
    *(f32x4*)((BUF) + w0       ) = ST0;                                  \
    *(f32x4*)((BUF) + w1       ) = ST1;                                  \
    *(f32x4*)((BUF) + w0 + 2048) = ST2;                                  \
    *(f32x4*)((BUF) + w1 + 2048) = ST3;                                  \
    const float* w2p = Wh2 + (JB) + q * 8;                               \
    f32x4 w20a = *(const f32x4*)(w2p);                                   \
    f32x4 w21a = *(const f32x4*)(w2p + 4);                               \
    f32x4 w20b = *(const f32x4*)(w2p + 32);                              \
    f32x4 w21b = *(const f32x4*)(w2p + 36);                              \
    const unsigned short* bp = bbase + (JB);                             \
    short8 ba0 = *(const short8*)(bp);                                   \
    short8 ba1 = *(const short8*)(bp + 16 * NN);                         \
    short8 ba2 = *(const short8*)(bp + 32 * NN);                         \
    short8 ba3 = *(const short8*)(bp + 48 * NN);                         \
    short8 bb0 = *(const short8*)(bp + 32);                              \
    short8 bb1 = *(const short8*)(bp + 32 + 16 * NN);                    \
    short8 bb2 = *(const short8*)(bp + 32 + 32 * NN);                    \
    short8 bb3 = *(const short8*)(bp + 32 + 48 * NN);                    \
    __builtin_amdgcn_sched_barrier(0);                                   \
    if (PF) {                                                            \
      ST0 = NTL(s0 + (SOFF)); ST1 = NTL(s1 + (SOFF));                    \
      ST2 = NTL(s2 + (SOFF)); ST3 = NTL(s3 + (SOFF));                    \
    }                                                                    \
    __builtin_amdgcn_sched_barrier(0);                                   \
    BLOCKC(BUF, 0,   w20a, w21a, ba0, ba1, ba2, ba3);                    \
    BLOCKC(BUF, 128, w20b, w21b, bb0, bb1, bb2, bb3);                    \
  }

__global__ __launch_bounds__(256, 4) void gat_phaseB(
    const float* __restrict__ adj, const unsigned short* __restrict__ Whbt,
    const float* __restrict__ Wh1, const float* __restrict__ Wh2,
    float* __restrict__ accbuf, float* __restrict__ denbuf, int nslices)
{
  const int wid  = threadIdx.x >> 6;
  const int lane = threadIdx.x & 63;
  const int task = blockIdx.x * 4 + wid;
  const int rowTile = task / SJ;
  const int jc      = task % SJ;
  const int m = lane & 15;
  const int q = lane >> 4;
  const int row = rowTile * 16 + m;
  const float wh1 = Wh1[row];
  // B-frag base: feature row (ft*16+m), k-slice q*8
  const unsigned short* bbase = Whbt + m * NN + q * 8;
  const int jbeg = jc * JCHUNK;

  __shared__ __align__(16) char ldsmem[4][2][4096];   // 32 KB / wg
  char* buf0 = &ldsmem[wid][0][0];
  char* buf1 = &ldsmem[wid][1][0];

  // write-side lane mapping: instr i covers rows i*4+r4, lane byte xw
  const int r4 = lane >> 4;
  const int xw = (lane & 15) * 16;
  const int mw0 = r4, mw1 = 4 + r4;
  const int w0 = mw0 * 256 + (xw ^ ((mw0 & 7) << 4));
  const int w1 = mw1 * 256 + (xw ^ ((mw1 & 7) << 4));
  // read-side swizzled fragment addresses (per lane, +BOFF/buf const)
  const int sw = (m & 7) << 4;
  const int rA = m * 256 + ((q * 32) ^ sw);
  const int rB = rA ^ 16;

  // coalesced adj src pointers: lane reads 16B at row (i*4+r4), byte xw of
  // the current tile's 256B row-chunk
  const char* s0 = (const char*)adj
                 + ((size_t)(rowTile * 16 + r4) * NN + jbeg) * 4 + xw;
  const char* s1 = s0 + (size_t)4  * NN * 4;
  const char* s2 = s0 + (size_t)8  * NN * 4;
  const char* s3 = s0 + (size_t)12 * NN * 4;

  f32x4 c0 = {0.f,0.f,0.f,0.f}, c1 = c0, c2 = c0, c3 = c0;
  float rsum = 0.f;

  // prologue: stage tiles 0 (bank A) and 1 (bank B)
  f32x4 stA0 = NTL(s0),       stA1 = NTL(s1),       stA2 = NTL(s2),       stA3 = NTL(s3);
  f32x4 stB0 = NTL(s0 + 256), stB1 = NTL(s1 + 256), stB2 = NTL(s2 + 256), stB3 = NTL(s3 + 256);
  s0 += 512; s1 += 512; s2 += 512; s3 += 512;   // -> tile 2

  for (int tt = 0; tt < 8; ++tt) {
    const int JB0 = jbeg + tt * 128;
    const bool pf = (tt < 7);
    // even tile 2tt (bank A, buf0); prefetch tile 2tt+2
    TILE_SECTION(stA0, stA1, stA2, stA3, buf0, JB0,      0,   pf);
    // odd tile 2tt+1 (bank B, buf1); prefetch tile 2tt+3
    TILE_SECTION(stB0, stB1, stB2, stB3, buf1, JB0 + 64, 256, pf);
    s0 += 512; s1 += 512; s2 += 512; s3 += 512;
  }

  // row-sum: combine the 4 k-quads; every lane ends with full sum for row m
  rsum += __shfl_xor(rsum, 16);
  rsum += __shfl_xor(rsum, 32);

  const int slice = (nslices > 1) ? jc : 0;
  float* accout = accbuf + (size_t)slice * (NN * FOUT);
  float* denout = denbuf + slice * NN;
  f32x4 cc[4] = {c0, c1, c2, c3};
  if (nslices > 1) {            // roomy ws: plain per-slice stores
    if (q == 0) denout[row] = rsum;
#pragma unroll
    for (int ft = 0; ft < 4; ++ft)
#pragma unroll
      for (int r = 0; r < 4; ++r)
        accout[(rowTile * 16 + q * 4 + r) * FOUT + ft * 16 + m] = cc[ft][r];
  } else {                      // tight ws: atomic accumulate (zeroed first)
    if (q == 0) atomicAdd(&denout[row], rsum);
#pragma unroll
    for (int ft = 0; ft < 4; ++ft)
#pragma unroll
      for (int r = 0; r < 4; ++r)
        atomicAdd(&accout[(rowTile * 16 + q * 4 + r) * FOUT + ft * 16 + m], cc[ft][r]);
  }
}

// ---------------------------------------------------------------- Phase C ---
// elu(acc/den), vectorized f32x4 per thread.
__global__ __launch_bounds__(256) void gat_phaseC(
    const float* __restrict__ accbuf, const float* __restrict__ denbuf,
    float* __restrict__ out, int nslices)
{
  const int idx4 = blockIdx.x * 256 + threadIdx.x;   // f32x4 index
  const int idx  = idx4 * 4;
  const int row  = idx >> 6;    // FOUT = 64; 4 elems stay within one row
  f32x4 s = {0.f, 0.f, 0.f, 0.f};
  float d = 0.f;
  for (int sl = 0; sl < nslices; ++sl) {
    f32x4 v = *(const f32x4*)(accbuf + (size_t)sl * (NN * FOUT) + idx);
    s += v;
    d += denbuf[sl * NN + row];
  }
  float inv = 1.0f / d;
  f32x4 o;
#pragma unroll
  for (int e = 0; e < 4; ++e) {
    float v = s[e] * inv;
    o[e] = (v > 0.f) ? v : expm1f(v);   // elu, alpha=1
  }
  *(f32x4*)(out + idx) = o;
}

// ------------------------------------------------------------------ launch --
extern "C" void kernel_launch(void* const* d_in, const int* in_sizes, int n_in,
                              void* d_out, int out_size, void* d_ws, size_t ws_size,
                              hipStream_t stream)
{
  const float* x   = (const float*)d_in[0];   // [8192,128]
  const float* adj = (const float*)d_in[1];   // [8192,8192]
  const float* W   = (const float*)d_in[2];   // [128,64]
  const float* a   = (const float*)d_in[3];   // [128,1]
  float* out = (float*)d_out;                 // [8192,64] fp32

  const size_t accEl = (size_t)NN * FOUT;
  const size_t roomyBytes = (size_t)SJ * accEl * 4 + (size_t)SJ * NN * 4
                          + (size_t)NN * 8 + (size_t)FOUT * NN * 2;
  const int nslices = (ws_size >= roomyBytes) ? SJ : 1;

  char* ws = (char*)d_ws;
  float* accbuf = (float*)ws;
  size_t off = (size_t)nslices * accEl * 4;
  float* denbuf = (float*)(ws + off); off += (size_t)nslices * NN * 4;
  float* Wh1 = (float*)(ws + off);    off += (size_t)NN * 4;
  float* Wh2 = (float*)(ws + off);    off += (size_t)NN * 4;
  unsigned short* Whbt = (unsigned short*)(ws + off);

  if (nslices == 1)   // atomic path needs zeroed acc+den (contiguous)
    hipMemsetAsync(accbuf, 0, accEl * 4 + (size_t)NN * 4, stream);

  gat_phaseA<<<NN / 16, 256, 0, stream>>>(x, W, a, Whbt, Wh1, Wh2);
  gat_phaseB<<<(512 * SJ) / 4, 256, 0, stream>>>(adj, Whbt, Wh1, Wh2,
                                                 accbuf, denbuf, nslices);
  gat_phaseC<<<(NN * FOUT) / 4 / 256, 256, 0, stream>>>(accbuf, denbuf, out, nslices);
}

// Round 5
// 395.962 us; speedup vs baseline: 1.1075x; 1.1075x over previous
//
#include <hip/hip_runtime.h>
#include <cstdint>
#include <cstddef>

// GAT layer, N=8192, Fin=128, Fout=64.
// h = elu( softmax_j(mask(leaky_relu(Wh1_i + Wh2_j))) @ Wh )
// R9: phaseB back to the proven R5 register-pipeline body (LDS adj staging was
// measured neutral in R7/R8), extended to 32 rows/wave (2 sub-tiles sharing
// every B-frag / Wh2 load). Rationale: R5/R7/R8 changed the adj path three
// ways with identical perf -> bottleneck is the Whbt B-frag stream (512 MB,
// 2x the adj bytes, 16KB-strided gathers). Sharing B across 2 row-tiles
// halves that term. SJ 8->16 keeps 4096 wave-tasks; nslices=16.

#define NN   8192
#define FIN  128
#define FOUT 64
#define SJ   16                // j-split per 32-row group: 256*SJ = 4096 tasks
#define JCHUNK (NN / SJ)       // 512 columns per wave -> 16 blocks of 32

typedef __attribute__((ext_vector_type(8))) short   short8;   // 8 bf16 (4 VGPRs)
typedef __attribute__((ext_vector_type(4))) float   f32x4;

#define LOG2E 1.44269504088896340736f
#define NTL(p) __builtin_nontemporal_load((const f32x4*)(p))

// ---------------------------------------------------------------- Phase A ---
// One wave per 4 rows: Wh[row][f] (f = lane), store bf16 transposed
// Whbt[f][row], wave-reduce Wh1 = Wh.a1, Wh2 = Wh.a2 (pre-scaled by log2e so
// phaseB uses exp2 directly; leaky_relu commutes with positive scaling).
__global__ __launch_bounds__(256) void gat_phaseA(
    const float* __restrict__ x, const float* __restrict__ W,
    const float* __restrict__ a, unsigned short* __restrict__ Whbt,
    float* __restrict__ Wh1, float* __restrict__ Wh2)
{
  const int wid  = threadIdx.x >> 6;
  const int lane = threadIdx.x & 63;
  const int row0 = (blockIdx.x * 4 + wid) * 4;
  const float a1 = a[lane];
  const float a2 = a[FOUT + lane];
  float acc[4] = {0.f, 0.f, 0.f, 0.f};
#pragma unroll 4
  for (int k = 0; k < FIN; k += 4) {
    float4 wv0 = make_float4(W[(k+0)*FOUT + lane], W[(k+1)*FOUT + lane],
                             W[(k+2)*FOUT + lane], W[(k+3)*FOUT + lane]);
#pragma unroll
    for (int r = 0; r < 4; ++r) {
      float4 xv = *(const float4*)(x + (row0 + r) * FIN + k);
      acc[r] = fmaf(xv.x, wv0.x, acc[r]);
      acc[r] = fmaf(xv.y, wv0.y, acc[r]);
      acc[r] = fmaf(xv.z, wv0.z, acc[r]);
      acc[r] = fmaf(xv.w, wv0.w, acc[r]);
    }
  }
#pragma unroll
  for (int r = 0; r < 4; ++r) {
    // bf16 round-to-nearest-even
    unsigned int u = __float_as_uint(acc[r]);
    unsigned int rb = (u + 0x7FFFu + ((u >> 16) & 1u)) >> 16;
    Whbt[lane * NN + row0 + r] = (unsigned short)rb;
    float s1 = acc[r] * a1, s2 = acc[r] * a2;
#pragma unroll
    for (int off = 32; off; off >>= 1) {
      s1 += __shfl_xor(s1, off);
      s2 += __shfl_xor(s2, off);
    }
    if (lane == 0) { Wh1[row0 + r] = s1 * LOG2E; Wh2[row0 + r] = s2 * LOG2E; }
  }
}

// ---------------------------------------------------------------- Phase B ---
// Wave task = (rowGroup of 32 rows) x (j-chunk of 512). Two 16-row sub-tiles
// share every B-frag and Wh2 load. A-frags (P) in registers: lane holds rows
// m=lane&15 (+0/+16), k=(lane>>4)*8+e. 16 column-blocks of 32, unrolled x2
// for static ping-pong: adj distance 2, Wh2/B-frags distance 1. Per body,
// issue order: [L2 next-block w2+B] -> af (consumes current regs) -> [adj
// prefetch block+2] -> 8 MFMA. In-order vmcnt: draining to current w2/B
// keeps the adj prefetch queue intact.
#define AF_ONE(AF, AD0, AD1, W20, W21, WH1, RS)                          \
    _Pragma("unroll")                                                    \
    for (int e = 0; e < 4; ++e) {                                        \
      float t0 = (WH1) + (W20)[e];                                       \
      t0 = fmaxf(t0, 0.2f * t0);            /* leaky_relu, scale-inv */  \
      float p0 = exp2f(t0) * (AD0)[e];      /* mask: adj is 0.0/1.0 */   \
      unsigned int pu0 = __float_as_uint(p0) & 0xFFFF0000u;              \
      RS += __uint_as_float(pu0);           /* denom matches bf16 num */ \
      AF[e] = (short)(pu0 >> 16);                                        \
      float t1 = (WH1) + (W21)[e];                                       \
      t1 = fmaxf(t1, 0.2f * t1);                                         \
      float p1 = exp2f(t1) * (AD1)[e];                                   \
      unsigned int pu1 = __float_as_uint(p1) & 0xFFFF0000u;              \
      RS += __uint_as_float(pu1);                                        \
      AF[4 + e] = (short)(pu1 >> 16);                                    \
    }

#define GAT_BODY(AD00, AD01, AD10, AD11, W2C0, W2C1, BC0, BC1, BC2, BC3, \
                 W2N0, W2N1, BN0, BN1, BN2, BN3, JN1, JN2)               \
  {                                                                      \
    W2N0 = *(const f32x4*)(w2base + (JN1));                              \
    W2N1 = *(const f32x4*)(w2base + (JN1) + 4);                          \
    BN0  = *(const short8*)(bbase + (JN1));                              \
    BN1  = *(const short8*)(bbase + (JN1) + 16 * NN);                    \
    BN2  = *(const short8*)(bbase + (JN1) + 32 * NN);                    \
    BN3  = *(const short8*)(bbase + (JN1) + 48 * NN);                    \
    short8 af0, af1;                                                     \
    AF_ONE(af0, AD00, AD01, W2C0, W2C1, wh1_0, rsum0);                   \
    AF_ONE(af1, AD10, AD11, W2C0, W2C1, wh1_1, rsum1);                   \
    AD00 = NTL(adjrow0 + (JN2)); AD01 = NTL(adjrow0 + (JN2) + 4);        \
    AD10 = NTL(adjrow1 + (JN2)); AD11 = NTL(adjrow1 + (JN2) + 4);        \
    c00 = __builtin_amdgcn_mfma_f32_16x16x32_bf16(af0, BC0, c00, 0,0,0); \
    c01 = __builtin_amdgcn_mfma_f32_16x16x32_bf16(af0, BC1, c01, 0,0,0); \
    c02 = __builtin_amdgcn_mfma_f32_16x16x32_bf16(af0, BC2, c02, 0,0,0); \
    c03 = __builtin_amdgcn_mfma_f32_16x16x32_bf16(af0, BC3, c03, 0,0,0); \
    c10 = __builtin_amdgcn_mfma_f32_16x16x32_bf16(af1, BC0, c10, 0,0,0); \
    c11 = __builtin_amdgcn_mfma_f32_16x16x32_bf16(af1, BC1, c11, 0,0,0); \
    c12 = __builtin_amdgcn_mfma_f32_16x16x32_bf16(af1, BC2, c12, 0,0,0); \
    c13 = __builtin_amdgcn_mfma_f32_16x16x32_bf16(af1, BC3, c13, 0,0,0); \
  }

__global__ __launch_bounds__(256, 3) void gat_phaseB(
    const float* __restrict__ adj, const unsigned short* __restrict__ Whbt,
    const float* __restrict__ Wh1, const float* __restrict__ Wh2,
    float* __restrict__ accbuf, float* __restrict__ denbuf, int nslices)
{
  const int wid  = threadIdx.x >> 6;
  const int lane = threadIdx.x & 63;
  const int task = blockIdx.x * 4 + wid;
  const int rg   = task / SJ;          // 32-row group
  const int jc   = task % SJ;
  const int m = lane & 15;
  const int q = lane >> 4;
  const int r0 = rg * 32 + m;
  const int r1 = r0 + 16;
  const float wh1_0 = Wh1[r0];
  const float wh1_1 = Wh1[r1];
  // per-lane bases with the q*8 element offset folded in
  const float* adjrow0 = adj + (size_t)r0 * NN + q * 8;
  const float* adjrow1 = adj + (size_t)r1 * NN + q * 8;
  const unsigned short* bbase = Whbt + m * NN + q * 8;   // feat row ft*16+m
  const float* w2base = Wh2 + q * 8;

  f32x4 c00 = {0.f,0.f,0.f,0.f}, c01 = c00, c02 = c00, c03 = c00;
  f32x4 c10 = c00, c11 = c00, c12 = c00, c13 = c00;
  float rsum0 = 0.f, rsum1 = 0.f;

  const int jbeg = jc * JCHUNK;

  // ping-pong slots: A = even blocks, B = odd blocks
  f32x4 w2A0, w2A1, w2B0, w2B1;
  short8 bA0, bA1, bA2, bA3, bB0, bB1, bB2, bB3;
  f32x4 adA00, adA01, adA10, adA11;    // sub-tile 0/1, block-even
  f32x4 adB00, adB01, adB10, adB11;    // block-odd

  // prologue: L2 data for block 0, adj for blocks 0 and 1
  w2A0 = *(const f32x4*)(w2base + jbeg);
  w2A1 = *(const f32x4*)(w2base + jbeg + 4);
  bA0  = *(const short8*)(bbase + jbeg);
  bA1  = *(const short8*)(bbase + jbeg + 16 * NN);
  bA2  = *(const short8*)(bbase + jbeg + 32 * NN);
  bA3  = *(const short8*)(bbase + jbeg + 48 * NN);
  adA00 = NTL(adjrow0 + jbeg);      adA01 = NTL(adjrow0 + jbeg + 4);
  adA10 = NTL(adjrow1 + jbeg);      adA11 = NTL(adjrow1 + jbeg + 4);
  adB00 = NTL(adjrow0 + jbeg + 32); adB01 = NTL(adjrow0 + jbeg + 36);
  adB10 = NTL(adjrow1 + jbeg + 32); adB11 = NTL(adjrow1 + jbeg + 36);

  // 16 blocks of 32 columns; unrolled x2 -> 8 static double-bodies. Tail
  // prefetches wrap to jbeg (valid addresses, values unused).
#pragma unroll
  for (int bb = 0; bb < 16; bb += 2) {
    const int j1 = (bb + 1 < 16) ? (bb + 1) * 32 : 0;
    const int j2 = (bb + 2 < 16) ? (bb + 2) * 32 : 0;
    const int j3 = (bb + 3 < 16) ? (bb + 3) * 32 : 0;
    GAT_BODY(adA00, adA01, adA10, adA11, w2A0, w2A1, bA0, bA1, bA2, bA3,
             w2B0, w2B1, bB0, bB1, bB2, bB3, jbeg + j1, jbeg + j2);
    GAT_BODY(adB00, adB01, adB10, adB11, w2B0, w2B1, bB0, bB1, bB2, bB3,
             w2A0, w2A1, bA0, bA1, bA2, bA3, jbeg + j2, jbeg + j3);
  }

  // row-sums: combine the 4 k-quads; every lane ends with full sum for its m
  rsum0 += __shfl_xor(rsum0, 16);
  rsum0 += __shfl_xor(rsum0, 32);
  rsum1 += __shfl_xor(rsum1, 16);
  rsum1 += __shfl_xor(rsum1, 32);

  const int slice = (nslices > 1) ? jc : 0;
  float* accout = accbuf + (size_t)slice * (NN * FOUT);
  float* denout = denbuf + slice * NN;
  f32x4 cc0[4] = {c00, c01, c02, c03};
  f32x4 cc1[4] = {c10, c11, c12, c13};
  if (nslices > 1) {            // roomy ws: plain per-slice stores
    if (q == 0) { denout[r0] = rsum0; denout[r1] = rsum1; }
#pragma unroll
    for (int ft = 0; ft < 4; ++ft)
#pragma unroll
      for (int r = 0; r < 4; ++r) {
        accout[(rg * 32 +      q * 4 + r) * FOUT + ft * 16 + m] = cc0[ft][r];
        accout[(rg * 32 + 16 + q * 4 + r) * FOUT + ft * 16 + m] = cc1[ft][r];
      }
  } else {                      // tight ws: atomic accumulate (zeroed first)
    if (q == 0) { atomicAdd(&denout[r0], rsum0); atomicAdd(&denout[r1], rsum1); }
#pragma unroll
    for (int ft = 0; ft < 4; ++ft)
#pragma unroll
      for (int r = 0; r < 4; ++r) {
        atomicAdd(&accout[(rg * 32 +      q * 4 + r) * FOUT + ft * 16 + m], cc0[ft][r]);
        atomicAdd(&accout[(rg * 32 + 16 + q * 4 + r) * FOUT + ft * 16 + m], cc1[ft][r]);
      }
  }
}

// ---------------------------------------------------------------- Phase C ---
// elu(acc/den), vectorized f32x4 per thread.
__global__ __launch_bounds__(256) void gat_phaseC(
    const float* __restrict__ accbuf, const float* __restrict__ denbuf,
    float* __restrict__ out, int nslices)
{
  const int idx4 = blockIdx.x * 256 + threadIdx.x;   // f32x4 index
  const int idx  = idx4 * 4;
  const int row  = idx >> 6;    // FOUT = 64; 4 elems stay within one row
  f32x4 s = {0.f, 0.f, 0.f, 0.f};
  float d = 0.f;
  for (int sl = 0; sl < nslices; ++sl) {
    f32x4 v = *(const f32x4*)(accbuf + (size_t)sl * (NN * FOUT) + idx);
    s += v;
    d += denbuf[sl * NN + row];
  }
  float inv = 1.0f / d;
  f32x4 o;
#pragma unroll
  for (int e = 0; e < 4; ++e) {
    float v = s[e] * inv;
    o[e] = (v > 0.f) ? v : expm1f(v);   // elu, alpha=1
  }
  *(f32x4*)(out + idx) = o;
}

// ------------------------------------------------------------------ launch --
extern "C" void kernel_launch(void* const* d_in, const int* in_sizes, int n_in,
                              void* d_out, int out_size, void* d_ws, size_t ws_size,
                              hipStream_t stream)
{
  const float* x   = (const float*)d_in[0];   // [8192,128]
  const float* adj = (const float*)d_in[1];   // [8192,8192]
  const float* W   = (const float*)d_in[2];   // [128,64]
  const float* a   = (const float*)d_in[3];   // [128,1]
  float* out = (float*)d_out;                 // [8192,64] fp32

  const size_t accEl = (size_t)NN * FOUT;
  const size_t roomyBytes = (size_t)SJ * accEl * 4 + (size_t)SJ * NN * 4
                          + (size_t)NN * 8 + (size_t)FOUT * NN * 2;
  const int nslices = (ws_size >= roomyBytes) ? SJ : 1;

  char* ws = (char*)d_ws;
  float* accbuf = (float*)ws;
  size_t off = (size_t)nslices * accEl * 4;
  float* denbuf = (float*)(ws + off); off += (size_t)nslices * NN * 4;
  float* Wh1 = (float*)(ws + off);    off += (size_t)NN * 4;
  float* Wh2 = (float*)(ws + off);    off += (size_t)NN * 4;
  unsigned short* Whbt = (unsigned short*)(ws + off);

  if (nslices == 1)   // atomic path needs zeroed acc+den (contiguous)
    hipMemsetAsync(accbuf, 0, accEl * 4 + (size_t)NN * 4, stream);

  gat_phaseA<<<NN / 16, 256, 0, stream>>>(x, W, a, Whbt, Wh1, Wh2);
  gat_phaseB<<<((NN / 32) * SJ) / 4, 256, 0, stream>>>(adj, Whbt, Wh1, Wh2,
                                                       accbuf, denbuf, nslices);
  gat_phaseC<<<(NN * FOUT) / 4 / 256, 256, 0, stream>>>(accbuf, denbuf, out, nslices);
}

// Round 6
// 393.371 us; speedup vs baseline: 1.1148x; 1.0066x over previous
//
#include <hip/hip_runtime.h>
#include <cstdint>
#include <cstddef>

// GAT layer, N=8192, Fin=128, Fout=64.
// h = elu( softmax_j(mask(leaky_relu(Wh1_i + Wh2_j))) @ Wh )
// R10 = R9 with ONE change: task mapping. The 4 waves of a workgroup now
// process 4 different 32-row groups at the SAME j-chunk -> identical Whbt
// B-frag / Wh2 addresses every block -> CU L1 serves 3 of 4 waves, cutting
// the Whbt L2 stream ~4x (the R9-confirmed bottleneck term). Bonus: blocks
// sharing a j-chunk are congruent mod 8 -> same XCD -> j-slice L2-hot.

#define NN   8192
#define FIN  128
#define FOUT 64
#define SJ   16                // j-split per 32-row group: 256*SJ = 4096 tasks
#define JCHUNK (NN / SJ)       // 512 columns per wave -> 16 blocks of 32

typedef __attribute__((ext_vector_type(8))) short   short8;   // 8 bf16 (4 VGPRs)
typedef __attribute__((ext_vector_type(4))) float   f32x4;

#define LOG2E 1.44269504088896340736f
#define NTL(p) __builtin_nontemporal_load((const f32x4*)(p))

// ---------------------------------------------------------------- Phase A ---
// One wave per 4 rows: Wh[row][f] (f = lane), store bf16 transposed
// Whbt[f][row], wave-reduce Wh1 = Wh.a1, Wh2 = Wh.a2 (pre-scaled by log2e so
// phaseB uses exp2 directly; leaky_relu commutes with positive scaling).
__global__ __launch_bounds__(256) void gat_phaseA(
    const float* __restrict__ x, const float* __restrict__ W,
    const float* __restrict__ a, unsigned short* __restrict__ Whbt,
    float* __restrict__ Wh1, float* __restrict__ Wh2)
{
  const int wid  = threadIdx.x >> 6;
  const int lane = threadIdx.x & 63;
  const int row0 = (blockIdx.x * 4 + wid) * 4;
  const float a1 = a[lane];
  const float a2 = a[FOUT + lane];
  float acc[4] = {0.f, 0.f, 0.f, 0.f};
#pragma unroll 4
  for (int k = 0; k < FIN; k += 4) {
    float4 wv0 = make_float4(W[(k+0)*FOUT + lane], W[(k+1)*FOUT + lane],
                             W[(k+2)*FOUT + lane], W[(k+3)*FOUT + lane]);
#pragma unroll
    for (int r = 0; r < 4; ++r) {
      float4 xv = *(const float4*)(x + (row0 + r) * FIN + k);
      acc[r] = fmaf(xv.x, wv0.x, acc[r]);
      acc[r] = fmaf(xv.y, wv0.y, acc[r]);
      acc[r] = fmaf(xv.z, wv0.z, acc[r]);
      acc[r] = fmaf(xv.w, wv0.w, acc[r]);
    }
  }
#pragma unroll
  for (int r = 0; r < 4; ++r) {
    // bf16 round-to-nearest-even
    unsigned int u = __float_as_uint(acc[r]);
    unsigned int rb = (u + 0x7FFFu + ((u >> 16) & 1u)) >> 16;
    Whbt[lane * NN + row0 + r] = (unsigned short)rb;
    float s1 = acc[r] * a1, s2 = acc[r] * a2;
#pragma unroll
    for (int off = 32; off; off >>= 1) {
      s1 += __shfl_xor(s1, off);
      s2 += __shfl_xor(s2, off);
    }
    if (lane == 0) { Wh1[row0 + r] = s1 * LOG2E; Wh2[row0 + r] = s2 * LOG2E; }
  }
}

// ---------------------------------------------------------------- Phase B ---
// Wave task = (rowGroup of 32 rows) x (j-chunk of 512). Two 16-row sub-tiles
// share every B-frag and Wh2 load; 4 waves/WG share the j-chunk (L1 merges
// their identical B/Wh2 streams). A-frags (P) in registers: lane holds rows
// m=lane&15 (+0/+16), k=(lane>>4)*8+e. 16 column-blocks of 32, unrolled x2
// for static ping-pong: adj distance 2, Wh2/B-frags distance 1. Per body,
// issue order: [L2 next-block w2+B] -> af (consumes current regs) -> [adj
// prefetch block+2] -> 8 MFMA. In-order vmcnt: draining to current w2/B
// keeps the adj prefetch queue intact.
#define AF_ONE(AF, AD0, AD1, W20, W21, WH1, RS)                          \
    _Pragma("unroll")                                                    \
    for (int e = 0; e < 4; ++e) {                                        \
      float t0 = (WH1) + (W20)[e];                                       \
      t0 = fmaxf(t0, 0.2f * t0);            /* leaky_relu, scale-inv */  \
      float p0 = exp2f(t0) * (AD0)[e];      /* mask: adj is 0.0/1.0 */   \
      unsigned int pu0 = __float_as_uint(p0) & 0xFFFF0000u;              \
      RS += __uint_as_float(pu0);           /* denom matches bf16 num */ \
      AF[e] = (short)(pu0 >> 16);                                        \
      float t1 = (WH1) + (W21)[e];                                       \
      t1 = fmaxf(t1, 0.2f * t1);                                         \
      float p1 = exp2f(t1) * (AD1)[e];                                   \
      unsigned int pu1 = __float_as_uint(p1) & 0xFFFF0000u;              \
      RS += __uint_as_float(pu1);                                        \
      AF[4 + e] = (short)(pu1 >> 16);                                    \
    }

#define GAT_BODY(AD00, AD01, AD10, AD11, W2C0, W2C1, BC0, BC1, BC2, BC3, \
                 W2N0, W2N1, BN0, BN1, BN2, BN3, JN1, JN2)               \
  {                                                                      \
    W2N0 = *(const f32x4*)(w2base + (JN1));                              \
    W2N1 = *(const f32x4*)(w2base + (JN1) + 4);                          \
    BN0  = *(const short8*)(bbase + (JN1));                              \
    BN1  = *(const short8*)(bbase + (JN1) + 16 * NN);                    \
    BN2  = *(const short8*)(bbase + (JN1) + 32 * NN);                    \
    BN3  = *(const short8*)(bbase + (JN1) + 48 * NN);                    \
    short8 af0, af1;                                                     \
    AF_ONE(af0, AD00, AD01, W2C0, W2C1, wh1_0, rsum0);                   \
    AF_ONE(af1, AD10, AD11, W2C0, W2C1, wh1_1, rsum1);                   \
    AD00 = NTL(adjrow0 + (JN2)); AD01 = NTL(adjrow0 + (JN2) + 4);        \
    AD10 = NTL(adjrow1 + (JN2)); AD11 = NTL(adjrow1 + (JN2) + 4);        \
    c00 = __builtin_amdgcn_mfma_f32_16x16x32_bf16(af0, BC0, c00, 0,0,0); \
    c01 = __builtin_amdgcn_mfma_f32_16x16x32_bf16(af0, BC1, c01, 0,0,0); \
    c02 = __builtin_amdgcn_mfma_f32_16x16x32_bf16(af0, BC2, c02, 0,0,0); \
    c03 = __builtin_amdgcn_mfma_f32_16x16x32_bf16(af0, BC3, c03, 0,0,0); \
    c10 = __builtin_amdgcn_mfma_f32_16x16x32_bf16(af1, BC0, c10, 0,0,0); \
    c11 = __builtin_amdgcn_mfma_f32_16x16x32_bf16(af1, BC1, c11, 0,0,0); \
    c12 = __builtin_amdgcn_mfma_f32_16x16x32_bf16(af1, BC2, c12, 0,0,0); \
    c13 = __builtin_amdgcn_mfma_f32_16x16x32_bf16(af1, BC3, c13, 0,0,0); \
  }

__global__ __launch_bounds__(256, 3) void gat_phaseB(
    const float* __restrict__ adj, const unsigned short* __restrict__ Whbt,
    const float* __restrict__ Wh1, const float* __restrict__ Wh2,
    float* __restrict__ accbuf, float* __restrict__ denbuf, int nslices)
{
  const int wid  = threadIdx.x >> 6;
  const int lane = threadIdx.x & 63;
  // R10 mapping: 4 waves of a WG share the j-chunk, cover 4 row-groups
  const int jc   = blockIdx.x % SJ;
  const int rg   = (blockIdx.x / SJ) * 4 + wid;   // 32-row group
  const int m = lane & 15;
  const int q = lane >> 4;
  const int r0 = rg * 32 + m;
  const int r1 = r0 + 16;
  const float wh1_0 = Wh1[r0];
  const float wh1_1 = Wh1[r1];
  // per-lane bases with the q*8 element offset folded in
  const float* adjrow0 = adj + (size_t)r0 * NN + q * 8;
  const float* adjrow1 = adj + (size_t)r1 * NN + q * 8;
  const unsigned short* bbase = Whbt + m * NN + q * 8;   // feat row ft*16+m
  const float* w2base = Wh2 + q * 8;

  f32x4 c00 = {0.f,0.f,0.f,0.f}, c01 = c00, c02 = c00, c03 = c00;
  f32x4 c10 = c00, c11 = c00, c12 = c00, c13 = c00;
  float rsum0 = 0.f, rsum1 = 0.f;

  const int jbeg = jc * JCHUNK;

  // ping-pong slots: A = even blocks, B = odd blocks
  f32x4 w2A0, w2A1, w2B0, w2B1;
  short8 bA0, bA1, bA2, bA3, bB0, bB1, bB2, bB3;
  f32x4 adA00, adA01, adA10, adA11;    // sub-tile 0/1, block-even
  f32x4 adB00, adB01, adB10, adB11;    // block-odd

  // prologue: L2 data for block 0, adj for blocks 0 and 1
  w2A0 = *(const f32x4*)(w2base + jbeg);
  w2A1 = *(const f32x4*)(w2base + jbeg + 4);
  bA0  = *(const short8*)(bbase + jbeg);
  bA1  = *(const short8*)(bbase + jbeg + 16 * NN);
  bA2  = *(const short8*)(bbase + jbeg + 32 * NN);
  bA3  = *(const short8*)(bbase + jbeg + 48 * NN);
  adA00 = NTL(adjrow0 + jbeg);      adA01 = NTL(adjrow0 + jbeg + 4);
  adA10 = NTL(adjrow1 + jbeg);      adA11 = NTL(adjrow1 + jbeg + 4);
  adB00 = NTL(adjrow0 + jbeg + 32); adB01 = NTL(adjrow0 + jbeg + 36);
  adB10 = NTL(adjrow1 + jbeg + 32); adB11 = NTL(adjrow1 + jbeg + 36);

  // 16 blocks of 32 columns; unrolled x2 -> 8 static double-bodies. Tail
  // prefetches wrap to jbeg (valid addresses, values unused).
#pragma unroll
  for (int bb = 0; bb < 16; bb += 2) {
    const int j1 = (bb + 1 < 16) ? (bb + 1) * 32 : 0;
    const int j2 = (bb + 2 < 16) ? (bb + 2) * 32 : 0;
    const int j3 = (bb + 3 < 16) ? (bb + 3) * 32 : 0;
    GAT_BODY(adA00, adA01, adA10, adA11, w2A0, w2A1, bA0, bA1, bA2, bA3,
             w2B0, w2B1, bB0, bB1, bB2, bB3, jbeg + j1, jbeg + j2);
    GAT_BODY(adB00, adB01, adB10, adB11, w2B0, w2B1, bB0, bB1, bB2, bB3,
             w2A0, w2A1, bA0, bA1, bA2, bA3, jbeg + j2, jbeg + j3);
  }

  // row-sums: combine the 4 k-quads; every lane ends with full sum for its m
  rsum0 += __shfl_xor(rsum0, 16);
  rsum0 += __shfl_xor(rsum0, 32);
  rsum1 += __shfl_xor(rsum1, 16);
  rsum1 += __shfl_xor(rsum1, 32);

  const int slice = (nslices > 1) ? jc : 0;
  float* accout = accbuf + (size_t)slice * (NN * FOUT);
  float* denout = denbuf + slice * NN;
  f32x4 cc0[4] = {c00, c01, c02, c03};
  f32x4 cc1[4] = {c10, c11, c12, c13};
  if (nslices > 1) {            // roomy ws: plain per-slice stores
    if (q == 0) { denout[r0] = rsum0; denout[r1] = rsum1; }
#pragma unroll
    for (int ft = 0; ft < 4; ++ft)
#pragma unroll
      for (int r = 0; r < 4; ++r) {
        accout[(rg * 32 +      q * 4 + r) * FOUT + ft * 16 + m] = cc0[ft][r];
        accout[(rg * 32 + 16 + q * 4 + r) * FOUT + ft * 16 + m] = cc1[ft][r];
      }
  } else {                      // tight ws: atomic accumulate (zeroed first)
    if (q == 0) { atomicAdd(&denout[r0], rsum0); atomicAdd(&denout[r1], rsum1); }
#pragma unroll
    for (int ft = 0; ft < 4; ++ft)
#pragma unroll
      for (int r = 0; r < 4; ++r) {
        atomicAdd(&accout[(rg * 32 +      q * 4 + r) * FOUT + ft * 16 + m], cc0[ft][r]);
        atomicAdd(&accout[(rg * 32 + 16 + q * 4 + r) * FOUT + ft * 16 + m], cc1[ft][r]);
      }
  }
}

// ---------------------------------------------------------------- Phase C ---
// elu(acc/den), vectorized f32x4 per thread.
__global__ __launch_bounds__(256) void gat_phaseC(
    const float* __restrict__ accbuf, const float* __restrict__ denbuf,
    float* __restrict__ out, int nslices)
{
  const int idx4 = blockIdx.x * 256 + threadIdx.x;   // f32x4 index
  const int idx  = idx4 * 4;
  const int row  = idx >> 6;    // FOUT = 64; 4 elems stay within one row
  f32x4 s = {0.f, 0.f, 0.f, 0.f};
  float d = 0.f;
  for (int sl = 0; sl < nslices; ++sl) {
    f32x4 v = *(const f32x4*)(accbuf + (size_t)sl * (NN * FOUT) + idx);
    s += v;
    d += denbuf[sl * NN + row];
  }
  float inv = 1.0f / d;
  f32x4 o;
#pragma unroll
  for (int e = 0; e < 4; ++e) {
    float v = s[e] * inv;
    o[e] = (v > 0.f) ? v : expm1f(v);   // elu, alpha=1
  }
  *(f32x4*)(out + idx) = o;
}

// ------------------------------------------------------------------ launch --
extern "C" void kernel_launch(void* const* d_in, const int* in_sizes, int n_in,
                              void* d_out, int out_size, void* d_ws, size_t ws_size,
                              hipStream_t stream)
{
  const float* x   = (const float*)d_in[0];   // [8192,128]
  const float* adj = (const float*)d_in[1];   // [8192,8192]
  const float* W   = (const float*)d_in[2];   // [128,64]
  const float* a   = (const float*)d_in[3];   // [128,1]
  float* out = (float*)d_out;                 // [8192,64] fp32

  const size_t accEl = (size_t)NN * FOUT;
  const size_t roomyBytes = (size_t)SJ * accEl * 4 + (size_t)SJ * NN * 4
                          + (size_t)NN * 8 + (size_t)FOUT * NN * 2;
  const int nslices = (ws_size >= roomyBytes) ? SJ : 1;

  char* ws = (char*)d_ws;
  float* accbuf = (float*)ws;
  size_t off = (size_t)nslices * accEl * 4;
  float* denbuf = (float*)(ws + off); off += (size_t)nslices * NN * 4;
  float* Wh1 = (float*)(ws + off);    off += (size_t)NN * 4;
  float* Wh2 = (float*)(ws + off);    off += (size_t)NN * 4;
  unsigned short* Whbt = (unsigned short*)(ws + off);

  if (nslices == 1)   // atomic path needs zeroed acc+den (contiguous)
    hipMemsetAsync(accbuf, 0, accEl * 4 + (size_t)NN * 4, stream);

  gat_phaseA<<<NN / 16, 256, 0, stream>>>(x, W, a, Whbt, Wh1, Wh2);
  gat_phaseB<<<((NN / 32) * SJ) / 4, 256, 0, stream>>>(adj, Whbt, Wh1, Wh2,
                                                       accbuf, denbuf, nslices);
  gat_phaseC<<<(NN * FOUT) / 4 / 256, 256, 0, stream>>>(accbuf, denbuf, out, nslices);
}